// Round 1
// baseline (332.104 us; speedup 1.0000x reference)
//
#include <hip/hip_runtime.h>
#include <hip/hip_bf16.h>

#define N2 4096
#define D 128
#define DC 32          // D/4 float4 chunks per row
#define JT 64          // j-tile
#define IT 8           // i-rows per block
#define TAU_INV 10.0f

// Kernel 1: normalize rows of p=concat(z_i,z_j), extract labels.
__global__ __launch_bounds__(64) void prep_kernel(const float* __restrict__ zi,
                                                  const float* __restrict__ zj,
                                                  const long long* __restrict__ y,
                                                  float* __restrict__ q,
                                                  int* __restrict__ labels) {
    int row = blockIdx.x;
    int lane = threadIdx.x;        // 64 lanes, 2 floats each
    const float* src = (row < 2048) ? (zi + row * D) : (zj + (row - 2048) * D);
    float2 v = ((const float2*)src)[lane];
    float ss = v.x * v.x + v.y * v.y;
    #pragma unroll
    for (int off = 1; off < 64; off <<= 1) ss += __shfl_xor(ss, off);
    float inv = 1.0f / sqrtf(ss);   // norms ~ sqrt(128) >> eps, eps branch never taken
    float2 o; o.x = v.x * inv; o.y = v.y * inv;
    ((float2*)(q + row * D))[lane] = o;
    if (lane == 0) labels[row] = (int)y[row & 2047];
}

// Kernel 2: fused sim + masked log-softmax reductions.
// Block: 256 threads = 4 waves. Block owns IT=8 i-rows (wave w owns rows w*2, w*2+1).
// Loops over all j in JT=64 tiles staged in LDS (xor-swizzled float4 chunks).
__global__ __launch_bounds__(256) void main_kernel(const float* __restrict__ q,
                                                   const int* __restrict__ labels,
                                                   float* __restrict__ out) {
    __shared__ float4 sj[JT * DC];   // 32 KB, chunk c of row jj stored at jj*DC + (c ^ (jj&7))
    __shared__ float4 si[IT * DC];   // 4 KB, plain [i][c]

    int tid  = threadIdx.x;
    int wave = tid >> 6;
    int lane = tid & 63;
    int i0   = blockIdx.x * IT;

    // stage the 8 i-rows: 8*32 = 256 chunks, one per thread (coalesced)
    si[tid] = ((const float4*)q)[i0 * DC + tid];

    int myi0 = i0 + wave * 2;
    int l0 = labels[myi0];
    int l1 = labels[myi0 + 1];

    float se0 = 0.f, se1 = 0.f;      // sum of exp(sim), self excluded
    float sp0 = 0.f, sp1 = 0.f;      // sum of sim over positives
    float c0  = 0.f, c1  = 0.f;      // positive counts

    for (int j0 = 0; j0 < N2; j0 += JT) {
        __syncthreads();
        // stage j-tile: 64*32 = 2048 chunks, 8 per thread, coalesced global, swizzled LDS
        #pragma unroll
        for (int p = 0; p < 8; ++p) {
            int id = p * 256 + tid;
            int jj = id >> 5, c = id & 31;
            sj[jj * DC + (c ^ (jj & 7))] = ((const float4*)q)[(j0 + jj) * DC + c];
        }
        __syncthreads();

        const float4* a0 = si + (wave * 2) * DC;
        const float4* a1 = a0 + DC;
        float d0 = 0.f, d1 = 0.f;
        #pragma unroll
        for (int c = 0; c < DC; ++c) {
            float4 b  = sj[lane * DC + (c ^ (lane & 7))];  // conflict-free (xor swizzle)
            float4 x0 = a0[c];                             // wave-uniform -> broadcast
            float4 x1 = a1[c];
            d0 += x0.x * b.x + x0.y * b.y + x0.z * b.z + x0.w * b.w;
            d1 += x1.x * b.x + x1.y * b.y + x1.z * b.z + x1.w * b.w;
        }

        int jg = j0 + lane;
        int lj = labels[jg];
        float s0 = d0 * TAU_INV;
        float s1 = d1 * TAU_INV;
        bool self0 = (jg == myi0);
        bool self1 = (jg == myi0 + 1);
        se0 += self0 ? 0.0f : __expf(s0);
        se1 += self1 ? 0.0f : __expf(s1);
        if (!self0 && lj == l0) { sp0 += s0; c0 += 1.0f; }
        if (!self1 && lj == l1) { sp1 += s1; c1 += 1.0f; }
    }

    // wave-level reduction (each i-row owned by exactly one wave)
    #pragma unroll
    for (int off = 32; off; off >>= 1) {
        se0 += __shfl_down(se0, off);
        se1 += __shfl_down(se1, off);
        sp0 += __shfl_down(sp0, off);
        sp1 += __shfl_down(sp1, off);
        c0  += __shfl_down(c0,  off);
        c1  += __shfl_down(c1,  off);
    }
    if (lane == 0) {
        float v0 = sp0 / c0 - logf(se0);
        float v1 = sp1 / c1 - logf(se1);
        atomicAdd(out, -(v0 + v1) * (1.0f / (float)N2));
    }
}

extern "C" void kernel_launch(void* const* d_in, const int* in_sizes, int n_in,
                              void* d_out, int out_size, void* d_ws, size_t ws_size,
                              hipStream_t stream) {
    const float*     zi = (const float*)d_in[0];
    const float*     zj = (const float*)d_in[1];
    const long long* y  = (const long long*)d_in[2];
    float* out = (float*)d_out;

    float* q      = (float*)d_ws;                  // 4096*128 floats = 2 MB
    int*   labels = (int*)((char*)d_ws + N2 * D * sizeof(float));

    hipMemsetAsync(d_out, 0, sizeof(float), stream);
    prep_kernel<<<N2, 64, 0, stream>>>(zi, zj, y, q, labels);
    main_kernel<<<N2 / IT, 256, 0, stream>>>(q, labels, out);
}

// Round 2
// 106.848 us; speedup vs baseline: 3.1082x; 3.1082x over previous
//
#include <hip/hip_runtime.h>

#define N2 4096
#define D 128
#define TAU_INV 10.0f
#define JSL 8            // j-slices per i-tile row; grid = 128 * JSL

typedef __attribute__((ext_vector_type(8))) short bf16x8;
typedef __attribute__((ext_vector_type(16))) float floatx16;

__device__ __forceinline__ short f2bf(float f) {
    unsigned u = __float_as_uint(f);
    u = (u + 0x7fff + ((u >> 16) & 1)) >> 16;   // RNE
    return (short)u;
}

// Normalize rows of p = concat(z_i, z_j) in fp32, emit bf16 Q + int labels.
__global__ __launch_bounds__(64) void prep_kernel(const float* __restrict__ zi,
                                                  const float* __restrict__ zj,
                                                  const long long* __restrict__ y,
                                                  short* __restrict__ qb,
                                                  int* __restrict__ labels) {
    int row = blockIdx.x;
    int lane = threadIdx.x;                    // 64 lanes, 2 floats each
    const float* src = (row < 2048) ? (zi + row * D) : (zj + (row - 2048) * D);
    float2 v = ((const float2*)src)[lane];
    float ss = v.x * v.x + v.y * v.y;
    #pragma unroll
    for (int m = 1; m < 64; m <<= 1) ss += __shfl_xor(ss, m);
    float inv = 1.0f / sqrtf(ss);              // ||p|| ~ sqrt(128) >> eps
    short2 o;
    o.x = f2bf(v.x * inv);
    o.y = f2bf(v.y * inv);
    ((short2*)(qb + row * D))[lane] = o;
    if (lane == 0) labels[row] = (int)y[row & 2047];
}

// Each block: one 32-row i-tile x one 512-col j-slice. 4 waves; wave w does
// j-tiles w, w+4, w+8, w+12 (32 cols each). MFMA 32x32x16 bf16, K=128 (8 steps).
// A/B frags: lane holds row base+(lane&31), 8 contiguous bf16 at k*16+(lane>>5)*8.
// C/D: col = lane&31, row = (reg&3) + 8*(reg>>2) + 4*(lane>>5).
__global__ __launch_bounds__(256) void main_kernel(const short* __restrict__ qb,
                                                   const int* __restrict__ labels,
                                                   float* __restrict__ se_g,
                                                   float* __restrict__ sp_g,
                                                   float* __restrict__ cnt_g) {
    int tid = threadIdx.x;
    int wave = tid >> 6;
    int lane = tid & 63;
    int col  = lane & 31;
    int half = lane >> 5;
    int it = blockIdx.x >> 3;          // 0..127
    int js = blockIdx.x & (JSL - 1);   // 0..7
    int i0 = it * 32;

    // A fragments for this block's 32 i-rows (reused across all j-tiles)
    const short* ap = qb + (i0 + col) * D + half * 8;
    bf16x8 af[8];
    #pragma unroll
    for (int k = 0; k < 8; ++k) af[k] = *(const bf16x8*)(ap + k * 16);

    // row labels per accumulator register
    int rl[16];
    #pragma unroll
    for (int r = 0; r < 16; ++r) rl[r] = labels[i0 + (r & 3) + 8 * (r >> 2) + 4 * half];

    float se[16], sp[16], cnt[16];
    #pragma unroll
    for (int r = 0; r < 16; ++r) { se[r] = 0.f; sp[r] = 0.f; cnt[r] = 0.f; }

    #pragma unroll
    for (int t = 0; t < 4; ++t) {
        int j0 = js * (N2 / JSL) + (wave + 4 * t) * 32;
        const short* bp = qb + (j0 + col) * D + half * 8;
        bf16x8 bf[8];
        #pragma unroll
        for (int k = 0; k < 8; ++k) bf[k] = *(const bf16x8*)(bp + k * 16);

        floatx16 acc;
        #pragma unroll
        for (int r = 0; r < 16; ++r) acc[r] = 0.f;
        #pragma unroll
        for (int k = 0; k < 8; ++k)
            acc = __builtin_amdgcn_mfma_f32_32x32x16_bf16(af[k], bf[k], acc, 0, 0, 0);

        int cl = labels[j0 + col];
        int jcol = j0 + col;
        #pragma unroll
        for (int r = 0; r < 16; ++r) {
            int rowr = i0 + (r & 3) + 8 * (r >> 2) + 4 * half;
            float s = acc[r] * TAU_INV;
            float e = __expf(s);
            bool self = (rowr == jcol);
            if (self) e = 0.f;
            se[r] += e;
            bool pos = (rl[r] == cl) && !self;
            sp[r]  += pos ? s : 0.f;
            cnt[r] += pos ? 1.f : 0.f;
        }
    }

    // reduce across the 32 cols (stay within each 32-lane half) and accumulate
    #pragma unroll
    for (int r = 0; r < 16; ++r) {
        float a = se[r], b = sp[r], c = cnt[r];
        #pragma unroll
        for (int m = 1; m < 32; m <<= 1) {
            a += __shfl_xor(a, m);
            b += __shfl_xor(b, m);
            c += __shfl_xor(c, m);
        }
        if (col == 0) {
            int rowr = i0 + (r & 3) + 8 * (r >> 2) + 4 * half;
            atomicAdd(&se_g[rowr], a);
            atomicAdd(&sp_g[rowr], b);
            atomicAdd(&cnt_g[rowr], c);
        }
    }
}

__global__ __launch_bounds__(256) void finish_kernel(const float* __restrict__ se_g,
                                                     const float* __restrict__ sp_g,
                                                     const float* __restrict__ cnt_g,
                                                     float* __restrict__ out) {
    float local = 0.f;
    for (int i = threadIdx.x; i < N2; i += 256)
        local += sp_g[i] / cnt_g[i] - __logf(se_g[i]);
    #pragma unroll
    for (int m = 1; m < 64; m <<= 1) local += __shfl_xor(local, m);
    __shared__ float wsum[4];
    if ((threadIdx.x & 63) == 0) wsum[threadIdx.x >> 6] = local;
    __syncthreads();
    if (threadIdx.x == 0)
        out[0] = -(wsum[0] + wsum[1] + wsum[2] + wsum[3]) * (1.0f / (float)N2);
}

extern "C" void kernel_launch(void* const* d_in, const int* in_sizes, int n_in,
                              void* d_out, int out_size, void* d_ws, size_t ws_size,
                              hipStream_t stream) {
    const float*     zi = (const float*)d_in[0];
    const float*     zj = (const float*)d_in[1];
    const long long* y  = (const long long*)d_in[2];
    float* out = (float*)d_out;

    char* ws = (char*)d_ws;
    short* qb     = (short*)ws;                              // 4096*128*2B = 1 MB
    int*   labels = (int*)(ws + N2 * D * sizeof(short));     // 16 KB
    float* se_g   = (float*)(ws + N2 * D * sizeof(short) + N2 * sizeof(int));
    float* sp_g   = se_g + N2;
    float* cnt_g  = sp_g + N2;

    hipMemsetAsync(se_g, 0, 3 * N2 * sizeof(float), stream);
    prep_kernel<<<N2, 64, 0, stream>>>(zi, zj, y, qb, labels);
    main_kernel<<<128 * JSL, 256, 0, stream>>>(qb, labels, se_g, sp_g, cnt_g);
    finish_kernel<<<1, 256, 0, stream>>>(se_g, sp_g, cnt_g, out);
}